// Round 1
// 11250.492 us; speedup vs baseline: 1.6216x; 1.6216x over previous
//
#include <hip/hip_runtime.h>
#include <hip/hip_bf16.h>

typedef short bf16x8 __attribute__((ext_vector_type(8)));
typedef float f32x4  __attribute__((ext_vector_type(4)));

#define NB   128          // batch
#define NS   256          // seq
#define NI   512          // input dim
#define NO   512          // output vocab
#define NH   1024         // hidden
#define G3   3072         // 3*H

__device__ inline unsigned short f2bf(float f) {
    unsigned u = __builtin_bit_cast(unsigned, f);
    u += 0x7fffu + ((u >> 16) & 1u);          // round-to-nearest-even
    return (unsigned short)(u >> 16);
}
__device__ inline float bf2f(unsigned short h) {
    unsigned u = ((unsigned)h) << 16;
    return __builtin_bit_cast(float, u);
}
__device__ inline bf16x8 as_bf8(uint4 u) { return __builtin_bit_cast(bf16x8, u); }
// 3-way bf16 split: x ~= hi + mid + lo with residual <= 2^-27 |x|
__device__ inline void split3(float x, unsigned short& h1, unsigned short& h2, unsigned short& h3) {
    h1 = f2bf(x); float r1 = x - bf2f(h1);
    h2 = f2bf(r1); float r2 = r1 - bf2f(h2);
    h3 = f2bf(r2);
}

#define MF(acc, A_, B_) acc = __builtin_amdgcn_mfma_f32_16x16x32_bf16(A_, B_, acc, 0, 0, 0)

// ---------------------------------------------------------------- tidx -----
__global__ void k_tidx(const float* __restrict__ gt, const float* __restrict__ gotok,
                       int* __restrict__ tidx) {
    int m    = blockIdx.x * 4 + (threadIdx.x >> 6);
    int lane = threadIdx.x & 63;
    int s = m >> 7, b = m & 127;
    const float* src = (s == 0) ? gotok : gt + ((size_t)b * NS + (s - 1)) * NO;
    int idx = 0x7fffffff;
    for (int j = lane; j < NO; j += 64)
        if (src[j] > 0.5f) idx = min(idx, j);
    for (int off = 32; off; off >>= 1) idx = min(idx, __shfl_down(idx, off));
    if (lane == 0) tidx[m] = idx;
}

// ------------------------------------------------------------ weight split -
__global__ void k_split3(const float* __restrict__ in, unsigned short* __restrict__ o1,
                         unsigned short* __restrict__ o2, unsigned short* __restrict__ o3, int n) {
    int i = blockIdx.x * blockDim.x + threadIdx.x;
    if (i < n) { unsigned short a, b, c; split3(in[i], a, b, c); o1[i] = a; o2[i] = b; o3[i] = c; }
}
// compact split of W_ih[:, :512] (y-part), row stride 512
__global__ void k_split3I(const float* __restrict__ wih, unsigned short* __restrict__ o1,
                          unsigned short* __restrict__ o2, unsigned short* __restrict__ o3) {
    int i = blockIdx.x * blockDim.x + threadIdx.x;   // 0 .. 3072*512-1
    int g = i >> 9, k = i & 511;
    unsigned short a, b, c; split3(wih[(size_t)g * (NI + NO) + k], a, b, c);
    o1[i] = a; o2[i] = b; o3[i] = c;
}
// transpose the one-hot gather table: wOT[t][g] = w_ih[g][512+t]  (coalesced writes)
__global__ void k_wot(const float* __restrict__ w_ih, float* __restrict__ wOT) {
    int g = blockIdx.x * 256 + threadIdx.x;          // 0..3071
    int t = blockIdx.y;                              // 0..511
    wOT[(size_t)t * G3 + g] = w_ih[(size_t)g * (NI + NO) + NI + t];
}
// init: hF = hx, ring slot 15 planes = split(hx)
__global__ void k_h0(const float* __restrict__ hx, float* __restrict__ hF,
                     unsigned short* __restrict__ r1, unsigned short* __restrict__ r2,
                     unsigned short* __restrict__ r3) {
    int i = blockIdx.x * blockDim.x + threadIdx.x;   // 0..131071
    float v = hx[i];
    hF[i] = v;
    unsigned short a, b, c; split3(v, a, b, c);
    r1[15 * 131072 + i] = a; r2[15 * 131072 + i] = b; r3[15 * 131072 + i] = c;
}

// ----------------------------------------------------- input-gate chunk ----
// gi for 16 steps at once (no h dependence): [2048 rows = 16 slots x 128 b] x 3072.
// r,z -> giRZ fp32; n-gate -> stashed in pre_out (RMW'd later by k_step).
// 256 blocks x 512 thr: block = slot rg (128 rows, 8 waves x 16) x colgroup cg (192 cols).
__global__ __launch_bounds__(512) void k_gi16(
    const unsigned short* __restrict__ wi1, const unsigned short* __restrict__ wi2,
    const unsigned short* __restrict__ wi3,
    const float* __restrict__ y, const float* __restrict__ wOT,
    const float* __restrict__ b_ih, const float* __restrict__ b_hh,
    const int* __restrict__ tidx,
    float* __restrict__ giRZ, float* __restrict__ pre_out, int base) {
    int bid = blockIdx.x;
    int rg = bid & 15, cg = bid >> 4;
    int tid = threadIdx.x, lane = tid & 63, wave = tid >> 6;
    int col = lane & 15, quad = lane >> 4;
    int s = base + rg;
    int arow = wave * 16 + col;                       // batch row of the A fragment
    f32x4 acc[12] = {};
    const float* Yp = y + ((size_t)arow * NS + s) * NI + quad * 8;
    const uint4* B1 = (const uint4*)wi1 + (size_t)(cg * 192 + col) * 64 + quad;
    const uint4* B2 = (const uint4*)wi2 + (size_t)(cg * 192 + col) * 64 + quad;
    const uint4* B3 = (const uint4*)wi3 + (size_t)(cg * 192 + col) * 64 + quad;
    #pragma unroll 1
    for (int kk = 0; kk < 16; kk++) {
        float4 f0 = *(const float4*)(Yp + kk * 32);
        float4 f1 = *(const float4*)(Yp + kk * 32 + 4);
        float v[8] = {f0.x, f0.y, f0.z, f0.w, f1.x, f1.y, f1.z, f1.w};
        bf16x8 a1, a2, a3;
        #pragma unroll
        for (int e = 0; e < 8; e++) {
            unsigned short u1, u2, u3; split3(v[e], u1, u2, u3);
            a1[e] = (short)u1; a2[e] = (short)u2; a3[e] = (short)u3;
        }
        #pragma unroll
        for (int t = 0; t < 12; t++) {
            bf16x8 b1 = as_bf8(B1[t * 1024 + kk * 4]);
            bf16x8 b2 = as_bf8(B2[t * 1024 + kk * 4]);
            bf16x8 b3 = as_bf8(B3[t * 1024 + kk * 4]);
            MF(acc[t], a1, b1); MF(acc[t], a1, b2); MF(acc[t], a2, b1);
            MF(acc[t], a1, b3); MF(acc[t], a3, b1); MF(acc[t], a2, b2);
        }
    }
    int ti[4];
    #pragma unroll
    for (int r = 0; r < 4; r++) ti[r] = tidx[s * 128 + wave * 16 + quad * 4 + r];
    #pragma unroll
    for (int t = 0; t < 12; t++) {
        int cg3 = cg * 192 + t * 16 + col;            // 0..3071 (gate-major column)
        int g = cg3 >> 10, cc = cg3 & 1023;
        float bi = b_ih[cg3] + (g < 2 ? b_hh[cg3] : 0.f);   // bhn stays in k_step
        #pragma unroll
        for (int r = 0; r < 4; r++) {
            int b = wave * 16 + quad * 4 + r;
            float val = acc[t][r] + wOT[(size_t)ti[r] * G3 + cg3] + bi;
            if (g == 2) pre_out[((size_t)b * NS + s) * NH + cc] = val;
            else        giRZ[((((size_t)rg * 2 + g) * 128 + b) << 10) + cc] = val;
        }
    }
}

// -------------------------------------------------------------- GRU step ---
// Recurrent GEMM only (input projection hoisted to k_gi16).
// 256 blocks x 512 thr = 8 waves: 2 row-halves x 4 K-quarters, LDS reduce.
__global__ __launch_bounds__(512) void k_step(
    const unsigned short* __restrict__ rh1, const unsigned short* __restrict__ rh2,
    const unsigned short* __restrict__ rh3,                    // h ring planes [16][128*1024]
    const unsigned short* __restrict__ wh1, const unsigned short* __restrict__ wh2,
    const unsigned short* __restrict__ wh3,                    // W_hh planes [3072*1024]
    const float* __restrict__ b_hh,
    const float* __restrict__ giRZ,                            // [16][2][128][1024] fp32
    float* __restrict__ hF,                                    // [128][1024] fp32 exact h
    unsigned short* __restrict__ oh1, unsigned short* __restrict__ oh2,
    unsigned short* __restrict__ oh3,                          // = rh1/2/3 (cur slot written)
    float* __restrict__ pre_out, int s) {
    __shared__ f32x4 lred[3][2][3][64];                        // [kq-1][rowhalf][gate][lane]
    int bid = blockIdx.x;
    int c_tile = ((bid & 7) << 3) | ((bid >> 3) & 7);   // XCD-swizzled: each XCD owns 128 cols
    int mt = bid >> 6;
    int tid = threadIdx.x, lane = tid & 63, wave = tid >> 6;
    int rowhalf = wave & 1, kq = wave >> 1;
    int col = lane & 15, quad = lane >> 4;
    int m0 = mt * 32 + rowhalf * 16;
    int c0 = c_tile * 16;
    int p = (s + 15) & 15, q = s & 15;                  // ring slots: prev, cur
    f32x4 ar = {}, az = {}, anh = {};

    // prefetch epilogue operands (all produced by earlier kernels / prev step)
    float g_r[4], g_z[4], p_in[4], p_h[4];
    float bhn = 0.f;
    if (kq == 0) {
        int c = c0 + col;
        bhn = b_hh[2 * NH + c];
        #pragma unroll
        for (int r = 0; r < 4; r++) {
            int b = m0 + quad * 4 + r;
            g_r[r]  = giRZ[(((size_t)q * 2 + 0) * 128 + b) * 1024 + c];
            g_z[r]  = giRZ[(((size_t)q * 2 + 1) * 128 + b) * 1024 + c];
            p_in[r] = pre_out[((size_t)b * NS + s) * NH + c];
            p_h[r]  = hF[(size_t)b * NH + c];
        }
    }

    const uint4* A1 = (const uint4*)rh1 + (size_t)p * 16384 + (size_t)(m0 + col) * 128 + kq * 32 + quad;
    const uint4* A2 = (const uint4*)rh2 + (size_t)p * 16384 + (size_t)(m0 + col) * 128 + kq * 32 + quad;
    const uint4* A3 = (const uint4*)rh3 + (size_t)p * 16384 + (size_t)(m0 + col) * 128 + kq * 32 + quad;
    const uint4* B1 = (const uint4*)wh1 + (size_t)(c0 + col) * 128 + kq * 32 + quad;
    const uint4* B2 = (const uint4*)wh2 + (size_t)(c0 + col) * 128 + kq * 32 + quad;
    const uint4* B3 = (const uint4*)wh3 + (size_t)(c0 + col) * 128 + kq * 32 + quad;
    #pragma unroll 2
    for (int kk = 0; kk < 8; kk++) {
        bf16x8 a1 = as_bf8(A1[kk * 4]), a2 = as_bf8(A2[kk * 4]), a3 = as_bf8(A3[kk * 4]);
        {   // gate r
            bf16x8 b1 = as_bf8(B1[kk * 4]), b2 = as_bf8(B2[kk * 4]), b3 = as_bf8(B3[kk * 4]);
            MF(ar, a1, b1); MF(ar, a1, b2); MF(ar, a2, b1);
            MF(ar, a1, b3); MF(ar, a3, b1); MF(ar, a2, b2);
        }
        {   // gate z  (+1024 rows = +131072 uint4)
            bf16x8 b1 = as_bf8(B1[kk * 4 + 131072]), b2 = as_bf8(B2[kk * 4 + 131072]), b3 = as_bf8(B3[kk * 4 + 131072]);
            MF(az, a1, b1); MF(az, a1, b2); MF(az, a2, b1);
            MF(az, a1, b3); MF(az, a3, b1); MF(az, a2, b2);
        }
        {   // gate n
            bf16x8 b1 = as_bf8(B1[kk * 4 + 262144]), b2 = as_bf8(B2[kk * 4 + 262144]), b3 = as_bf8(B3[kk * 4 + 262144]);
            MF(anh, a1, b1); MF(anh, a1, b2); MF(anh, a2, b1);
            MF(anh, a1, b3); MF(anh, a3, b1); MF(anh, a2, b2);
        }
    }
    if (kq) {
        lred[kq - 1][rowhalf][0][lane] = ar;
        lred[kq - 1][rowhalf][1][lane] = az;
        lred[kq - 1][rowhalf][2][lane] = anh;
    }
    __syncthreads();
    if (kq == 0) {
        #pragma unroll
        for (int j = 0; j < 3; j++) {
            ar  += lred[j][rowhalf][0][lane];
            az  += lred[j][rowhalf][1][lane];
            anh += lred[j][rowhalf][2][lane];
        }
        int c = c0 + col;
        #pragma unroll
        for (int r = 0; r < 4; r++) {
            int b = m0 + quad * 4 + r;
            float sr = ar[r] + g_r[r];
            float sz = az[r] + g_z[r];
            float rg = 1.f / (1.f + expf(-sr));
            float zg = 1.f / (1.f + expf(-sz));
            float hn_ = anh[r] + bhn;
            float pre = p_in[r] + rg * hn_;
            float ng = tanhf(pre);
            float hy = ng + zg * (p_h[r] - ng);
            hF[(size_t)b * NH + c] = hy;
            pre_out[((size_t)b * NS + s) * NH + c] = pre;
            unsigned short u1, u2, u3; split3(hy, u1, u2, u3);
            size_t ro = (size_t)q * 131072 + (size_t)b * NH + c;
            oh1[ro] = u1; oh2[ro] = u2; oh3[ro] = u3;
        }
    }
}

// ------------------------------------------- logits+softmax+argmax (x16) ---
// one launch per 16 steps; 128 blocks = 16 slots x 8 batch-tiles of 16 rows.
__global__ __launch_bounds__(256) void k_logits16(
    const unsigned short* __restrict__ rh1, const unsigned short* __restrict__ rh2,
    const unsigned short* __restrict__ rh3,
    const unsigned short* __restrict__ lw1, const unsigned short* __restrict__ lw2,
    const unsigned short* __restrict__ lw3,
    const float* __restrict__ lin_b,
    float* __restrict__ probs, int* __restrict__ amax, int base) {
    __shared__ __align__(16) float lt[16 * 512];
    __shared__ float red[16 * 16];
    __shared__ int  redi[16 * 16];
    __shared__ float rmax[16], rsum[16];
    __shared__ int  ridx[16];
    int slot = blockIdx.x >> 3, b0 = (blockIdx.x & 7) * 16;
    int s = base + slot;
    int tid = threadIdx.x, lane = tid & 63, wave = tid >> 6;
    int col = lane & 15, quad = lane >> 4;
    f32x4 acc[8] = {};
    const uint4* A1 = (const uint4*)rh1 + (size_t)slot * 16384 + (size_t)(b0 + col) * 128 + quad;
    const uint4* A2 = (const uint4*)rh2 + (size_t)slot * 16384 + (size_t)(b0 + col) * 128 + quad;
    const uint4* A3 = (const uint4*)rh3 + (size_t)slot * 16384 + (size_t)(b0 + col) * 128 + quad;
    const uint4* B1 = (const uint4*)lw1 + (size_t)(wave * 128 + col) * 128 + quad;
    const uint4* B2 = (const uint4*)lw2 + (size_t)(wave * 128 + col) * 128 + quad;
    const uint4* B3 = (const uint4*)lw3 + (size_t)(wave * 128 + col) * 128 + quad;
    for (int kk = 0; kk < 32; kk++) {
        bf16x8 a1 = as_bf8(A1[kk * 4]), a2 = as_bf8(A2[kk * 4]), a3 = as_bf8(A3[kk * 4]);
        #pragma unroll
        for (int t = 0; t < 8; t++) {
            bf16x8 b1 = as_bf8(B1[kk * 4 + t * 2048]);
            bf16x8 b2 = as_bf8(B2[kk * 4 + t * 2048]);
            bf16x8 b3 = as_bf8(B3[kk * 4 + t * 2048]);
            MF(acc[t], a1, b1); MF(acc[t], a1, b2); MF(acc[t], a2, b1);
            MF(acc[t], a1, b3); MF(acc[t], a3, b1); MF(acc[t], a2, b2);
        }
    }
    #pragma unroll
    for (int t = 0; t < 8; t++) {
        int n = wave * 128 + t * 16 + col;
        float lb = lin_b[n];
        #pragma unroll
        for (int r = 0; r < 4; r++)
            lt[(quad * 4 + r) * 512 + n] = acc[t][r] + lb;
    }
    __syncthreads();
    int r = tid >> 4, t16 = tid & 15;
    const float* row = lt + r * 512 + t16 * 32;
    float mx = row[0];
    for (int j = 1; j < 32; j++) mx = fmaxf(mx, row[j]);
    red[r * 16 + t16] = mx;
    __syncthreads();
    if (t16 == 0) {
        float m2 = red[r * 16];
        for (int j = 1; j < 16; j++) m2 = fmaxf(m2, red[r * 16 + j]);
        rmax[r] = m2;
    }
    __syncthreads();
    float RM = rmax[r];
    float sum = 0.f; int ai = 0x7fffffff;
    for (int j = 0; j < 32; j++) {
        float v = row[j];
        sum += expf(v - RM);
        if (v == RM) ai = min(ai, t16 * 32 + j);
    }
    red[r * 16 + t16] = sum; redi[r * 16 + t16] = ai;
    __syncthreads();
    if (t16 == 0) {
        float s2 = 0.f; int i2 = 0x7fffffff;
        for (int j = 0; j < 16; j++) { s2 += red[r * 16 + j]; i2 = min(i2, redi[r * 16 + j]); }
        rsum[r] = s2; ridx[r] = i2;
    }
    __syncthreads();
    float inv = 1.f / rsum[r];
    int b = b0 + r;
    size_t off = ((size_t)b * NS + s) * NO + t16 * 32;
    for (int j = 0; j < 32; j++)
        probs[off + j] = expf(row[j] - RM) * inv;
    if (t16 == 0) amax[s * 128 + b] = ridx[r];
}

// one-hot sampled_output from amax
__global__ void k_samp(const int* __restrict__ amax, float* __restrict__ samp) {
    int m = blockIdx.x;                 // m = s*128+b
    int b = m & 127, s = m >> 7;
    int ai = amax[m];
    size_t off = ((size_t)b * NS + s) * NO;
    for (int j = threadIdx.x; j < NO; j += 256)
        samp[off + j] = (j == ai) ? 1.f : 0.f;
}

// ---------------------------------------------------------------- launch ---
extern "C" void kernel_launch(void* const* d_in, const int* in_sizes, int n_in,
                              void* d_out, int out_size, void* d_ws, size_t ws_size,
                              hipStream_t stream) {
    const float* y     = (const float*)d_in[0];
    const float* gt    = (const float*)d_in[1];
    const float* hx    = (const float*)d_in[2];
    const float* w_ih  = (const float*)d_in[3];
    const float* b_ih  = (const float*)d_in[4];
    const float* w_hh  = (const float*)d_in[5];
    const float* b_hh  = (const float*)d_in[6];
    const float* lw    = (const float*)d_in[7];
    const float* lb    = (const float*)d_in[8];
    const float* gotok = (const float*)d_in[9];

    // workspace — total 44,826,624 B (~44.8 MB), unchanged from baseline
    char* ws = (char*)d_ws;
    unsigned short* wh1 = (unsigned short*)(ws);                  // 6,291,456 B
    unsigned short* wh2 = (unsigned short*)(ws + 6291456ull);     // 6,291,456
    unsigned short* wh3 = (unsigned short*)(ws + 12582912ull);    // 6,291,456
    unsigned short* wi1 = (unsigned short*)(ws + 18874368ull);    // 3,145,728
    unsigned short* wi2 = (unsigned short*)(ws + 22020096ull);    // 3,145,728
    unsigned short* wi3 = (unsigned short*)(ws + 25165824ull);    // 3,145,728
    unsigned short* lw1 = (unsigned short*)(ws + 28311552ull);    // 1,048,576
    unsigned short* lw2 = (unsigned short*)(ws + 29360128ull);    // 1,048,576
    unsigned short* lw3 = (unsigned short*)(ws + 30408704ull);    // 1,048,576
    unsigned short* rh1 = (unsigned short*)(ws + 31457280ull);    // 4,194,304 (16 slots)
    unsigned short* rh2 = (unsigned short*)(ws + 35651584ull);    // 4,194,304
    unsigned short* rh3 = (unsigned short*)(ws + 39845888ull);    // 4,194,304
    float*          hF  = (float*)(ws + 44040192ull);             //   524,288
    int*            tidx= (int*)(ws + 44564480ull);               //   131,072
    int*            amax= (int*)(ws + 44695552ull);               //   131,072

    float* out   = (float*)d_out;
    float* probs = out;                 // 16,777,216 elems
    float* pre   = out + 16777216;      // 33,554,432
    float* samp  = out + 50331648;      // 16,777,216 (written only by k_samp at end)
    float* hxf   = out + 67108864;      //    131,072

    // scratch carved out of the samp output region (overwritten by k_samp at end):
    float* giRZ = samp;                 // 16 slots x 2 gates x 128 b x 1024 = 4,194,304 floats
    float* wOT  = samp + 4194304;       // 512 x 3072 = 1,572,864 floats

    k_tidx<<<8192, 256, 0, stream>>>(gt, gotok, tidx);
    k_split3<<<12288, 256, 0, stream>>>(w_hh, wh1, wh2, wh3, 3145728);
    k_split3I<<<6144, 256, 0, stream>>>(w_ih, wi1, wi2, wi3);
    k_split3<<<2048, 256, 0, stream>>>(lw, lw1, lw2, lw3, 524288);
    k_h0<<<512, 256, 0, stream>>>(hx, hF, rh1, rh2, rh3);
    k_wot<<<dim3(12, 512), 256, 0, stream>>>(w_ih, wOT);

    k_gi16<<<256, 512, 0, stream>>>(wi1, wi2, wi3, y, wOT, b_ih, b_hh, tidx,
                                    giRZ, pre, 0);
    for (int s = 0; s < NS; s++) {
        k_step<<<256, 512, 0, stream>>>(rh1, rh2, rh3, wh1, wh2, wh3,
                                        b_hh, giRZ, hF, rh1, rh2, rh3, pre, s);
        if ((s & 15) == 15) {
            if (s < NS - 1)
                k_gi16<<<256, 512, 0, stream>>>(wi1, wi2, wi3, y, wOT, b_ih, b_hh, tidx,
                                                giRZ, pre, s + 1);
            k_logits16<<<128, 256, 0, stream>>>(rh1, rh2, rh3, lw1, lw2, lw3, lb,
                                                probs, amax, s - 15);
        }
    }

    k_samp<<<32768, 256, 0, stream>>>(amax, samp);
    hipMemcpyAsync(hxf, hF, 524288, hipMemcpyDeviceToDevice, stream);
}